// Round 2
// baseline (1082.383 us; speedup 1.0000x reference)
//
#include <hip/hip_runtime.h>

#define TT 2048
#define FF 32
#define CC 32              // chunk length (steps)
#define NCHUNK (TT / CC)   // 64

__device__ __forceinline__ float fast_exp2(float x) {
#if __has_builtin(__builtin_amdgcn_exp2f)
    return __builtin_amdgcn_exp2f(x);
#else
    return exp2f(x);
#endif
}
__device__ __forceinline__ float fast_rcp(float x) {
#if __has_builtin(__builtin_amdgcn_rcpf)
    return __builtin_amdgcn_rcpf(x);
#else
    return 1.0f / x;
#endif
}
__device__ __forceinline__ float fsig(float x) {
    // 1/(1+exp(-x)) = rcp(1 + exp2(-x*log2e))
    return fast_rcp(1.0f + fast_exp2(-1.442695041f * x));
}
__device__ __forceinline__ float ftanh(float x) {
    // tanh(x) = 2/(1+exp2(-2x*log2e)) - 1
    return fmaf(2.0f, fast_rcp(1.0f + fast_exp2(-2.885390082f * x)), -1.0f);
}

__global__ __launch_bounds__(256, 2)
void lstm_pc_kernel(const float* __restrict__ x,
                    const float* __restrict__ Wih,
                    const float* __restrict__ Whh,
                    const float* __restrict__ bih,
                    const float* __restrict__ bhh,
                    const float* __restrict__ Wlin,
                    const float* __restrict__ blin,
                    float* __restrict__ out)
{
    // LDS rings. Slot for chunk m: gbuf/hbuf/xbuf -> m&1, oxbuf -> m%3.
    __shared__ __align__(16) float gbuf[2][CC][128];  // gx = Wih@x + b (producer -> consumer)
    __shared__ __align__(16) float hbuf[2][CC][32];   // h history (consumer -> out-producer)
    __shared__ __align__(16) float oxbuf[3][CC][32];  // Wlin_odd @ x   (outx -> out)
    __shared__ __align__(16) float xbuf[2][CC][32];   // staged x chunk
    // total 60 KB -> 2 blocks/CU

    const int bid  = blockIdx.x;
    const int tid  = threadIdx.x;
    const int wid  = tid >> 6;
    const int lane = tid & 63;
    // roles: 0,1 = gx producers; 2 = outx(lo)/out(hi); 3 = consumer (recurrence)
    // rotate by block parity so co-resident blocks' consumers use different SIMDs
    const int role = (wid + ((bid & 1) << 1)) & 3;
    const int p    = (role < 2) ? role * 64 + lane : 0;   // gx row 0..127
    const int f2   = lane & 31;

    const float* __restrict__ xb = x + (size_t)bid * TT * FF;
    float* __restrict__ outb = out + (size_t)bid * TT * FF;

    // ---- per-role weight registers (exclusive paths share wa/wb) ----
    float wa[32], wb[32];
    float bias = 0.0f;
    if (role == 3) {
        const float4* A = (const float4*)(Whh + lane * 32);
        const float4* Bq = (const float4*)(Whh + (lane + 64) * 32);
#pragma unroll
        for (int q = 0; q < 8; q++) {
            float4 a = A[q], b = Bq[q];
            wa[4*q+0]=a.x; wa[4*q+1]=a.y; wa[4*q+2]=a.z; wa[4*q+3]=a.w;
            wb[4*q+0]=b.x; wb[4*q+1]=b.y; wb[4*q+2]=b.z; wb[4*q+3]=b.w;
        }
    } else if (role < 2) {
        const float4* A = (const float4*)(Wih + p * 32);
#pragma unroll
        for (int q = 0; q < 8; q++) {
            float4 a = A[q];
            wa[4*q+0]=a.x; wa[4*q+1]=a.y; wa[4*q+2]=a.z; wa[4*q+3]=a.w;
        }
        bias = bih[p] + bhh[p];
    } else {
        // lane<32: odd cols of Wlin row f2 (x part); lane>=32: even cols (h part)
        const int off = (lane < 32) ? 1 : 0;
#pragma unroll
        for (int j = 0; j < 32; j++) wa[j] = Wlin[f2 * 64 + 2 * j + off];
        bias = (lane < 32) ? 0.0f : blin[f2];
    }

    // consumer activation constants: lane<32 -> acc1 is g-row (tanh); else o-row (sigmoid)
    const bool low = lane < 32;
    const float sk  = low ? -2.885390082f : -1.442695041f;
    const float s2v = low ? 2.0f : 1.0f;
    const float s3v = low ? -1.0f : 0.0f;
    float hv = 0.0f, cv = 0.0f;

    // ---- role lambdas ----
    auto stage_x = [&](int m) {          // gx threads: stage x chunk m -> LDS
        const float4* xg = (const float4*)(xb + (size_t)m * CC * FF);
        float4* xw = (float4*)&xbuf[m & 1][0][0];
        float4 v0 = xg[2 * p], v1 = xg[2 * p + 1];
        xw[2 * p] = v0; xw[2 * p + 1] = v1;
    };

    auto gx_chunk = [&](int m) {         // rows p: gx[m][s][p] = Wih_p . x_s + bias
        const float* xs = &xbuf[m & 1][0][0];
        float* gb = &gbuf[m & 1][0][0];
#pragma unroll 2
        for (int s = 0; s < CC; s++) {
            const float4* x4 = (const float4*)(xs + s * 32);
            float a0 = 0.0f, a1 = 0.0f;
#pragma unroll
            for (int q = 0; q < 4; q++) {
                float4 u = x4[2 * q], v = x4[2 * q + 1];
                a0 = fmaf(wa[8*q+0], u.x, a0); a1 = fmaf(wa[8*q+1], u.y, a1);
                a0 = fmaf(wa[8*q+2], u.z, a0); a1 = fmaf(wa[8*q+3], u.w, a1);
                a0 = fmaf(wa[8*q+4], v.x, a0); a1 = fmaf(wa[8*q+5], v.y, a1);
                a0 = fmaf(wa[8*q+6], v.z, a0); a1 = fmaf(wa[8*q+7], v.w, a1);
            }
            gb[s * 128 + p] = a0 + a1 + bias;
        }
    };

    auto outx_chunk = [&](int m) {       // lanes<32 of role2: oxbuf[m][s][f] = Wlin_odd_f . x_s
        const float* xs = &xbuf[m & 1][0][0];
        float* oxb = &oxbuf[m % 3][0][0];
#pragma unroll 2
        for (int s = 0; s < CC; s++) {
            const float4* x4 = (const float4*)(xs + s * 32);
            float a0 = 0.0f, a1 = 0.0f;
#pragma unroll
            for (int q = 0; q < 4; q++) {
                float4 u = x4[2 * q], v = x4[2 * q + 1];
                a0 = fmaf(wa[8*q+0], u.x, a0); a1 = fmaf(wa[8*q+1], u.y, a1);
                a0 = fmaf(wa[8*q+2], u.z, a0); a1 = fmaf(wa[8*q+3], u.w, a1);
                a0 = fmaf(wa[8*q+4], v.x, a0); a1 = fmaf(wa[8*q+5], v.y, a1);
                a0 = fmaf(wa[8*q+6], v.z, a0); a1 = fmaf(wa[8*q+7], v.w, a1);
            }
            oxb[s * 32 + f2] = a0 + a1;
        }
    };

    auto out_chunk = [&](int m) {        // lanes>=32 of role2: out[b][m*C+s][f] = tanh(ox + Wlin_even_f . h_s + bl)
        const float* hs = &hbuf[m & 1][0][0];
        const float* oxs = &oxbuf[m % 3][0][0];
        float* ob = outb + (size_t)m * CC * FF;
#pragma unroll 2
        for (int s = 0; s < CC; s++) {
            const float4* h4 = (const float4*)(hs + s * 32);
            float a0 = 0.0f, a1 = 0.0f;
#pragma unroll
            for (int q = 0; q < 4; q++) {
                float4 u = h4[2 * q], v = h4[2 * q + 1];
                a0 = fmaf(wa[8*q+0], u.x, a0); a1 = fmaf(wa[8*q+1], u.y, a1);
                a0 = fmaf(wa[8*q+2], u.z, a0); a1 = fmaf(wa[8*q+3], u.w, a1);
                a0 = fmaf(wa[8*q+4], v.x, a0); a1 = fmaf(wa[8*q+5], v.y, a1);
                a0 = fmaf(wa[8*q+6], v.z, a0); a1 = fmaf(wa[8*q+7], v.w, a1);
            }
            ob[s * 32 + f2] = ftanh(a0 + a1 + oxs[s * 32 + f2] + bias);
        }
    };

    auto consumer_chunk = [&](int k) {   // recurrence for chunk k; one wave, no barriers inside
        const float* g0 = &gbuf[k & 1][0][0];
        float* hb = &hbuf[k & 1][0][0];
#pragma unroll 2
        for (int s = 0; s < CC; s++) {
            float gx0 = g0[s * 128 + lane];
            float gx1 = g0[s * 128 + 64 + lane];
            float acc0 = 0.0f, acc1 = 0.0f;
            unsigned hbits = __float_as_uint(hv);
#pragma unroll
            for (int j = 0; j < 32; j++) {
                float hj = __uint_as_float(__builtin_amdgcn_readlane(hbits, j));
                acc0 = fmaf(wa[j], hj, acc0);   // row lane     (i for low / f for high)
                acc1 = fmaf(wb[j], hj, acc1);   // row lane+64  (g for low / o for high)
            }
            acc0 += gx0; acc1 += gx1;
            float ia = fsig(acc0);                                      // i (low) / f (high)
            float ga = fmaf(s2v, fast_rcp(1.0f + fast_exp2(sk * acc1)), s3v); // g=tanh (low) / o=sig (high)
            float fgv = __shfl_xor(ia, 32);   // lanes<32 receive sigma(f-row)
            float oov = __shfl_xor(ga, 32);   // lanes<32 receive sigma(o-row)
            cv = fmaf(fgv, cv, ia * ga);      // c = f*c + i*g   (valid in lanes<32)
            float th = ftanh(cv);
            hv = oov * th;                    // h = o*tanh(c)   (valid in lanes<32)
            if (low) hb[s * 32 + lane] = hv;
        }
    };

    // ---- prologue: stage x[0],x[1]; compute gx[0], outx[0] ----
    if (role < 2) { stage_x(0); stage_x(1); }
    __syncthreads();
    if (role < 2) gx_chunk(0);
    if (role == 2 && lane < 32) outx_chunk(0);
    __syncthreads();

    // ---- main loop: 65 iterations; out for chunk k-1 trails by one ----
#pragma unroll 1
    for (int k = 0; k <= NCHUNK; k++) {
        if (role == 3) {
            if (k < NCHUNK) consumer_chunk(k);
        } else if (role < 2) {
            if (k + 1 < NCHUNK) gx_chunk(k + 1);
            if (k + 2 < NCHUNK) stage_x(k + 2);
        } else {
            if (lane < 32) { if (k + 1 < NCHUNK) outx_chunk(k + 1); }
            else           { if (k >= 1)         out_chunk(k - 1); }
        }
        __syncthreads();
    }
}

extern "C" void kernel_launch(void* const* d_in, const int* in_sizes, int n_in,
                              void* d_out, int out_size, void* d_ws, size_t ws_size,
                              hipStream_t stream) {
    const float* x    = (const float*)d_in[0];
    const float* Wih  = (const float*)d_in[1];
    const float* Whh  = (const float*)d_in[2];
    const float* bih  = (const float*)d_in[3];
    const float* bhh  = (const float*)d_in[4];
    const float* Wlin = (const float*)d_in[5];
    const float* blin = (const float*)d_in[6];
    float* out = (float*)d_out;
    (void)d_ws; (void)ws_size; (void)n_in; (void)out_size;

    const int B = in_sizes[0] / (TT * FF);   // 512
    hipLaunchKernelGGL(lstm_pc_kernel, dim3(B), dim3(256), 0, stream,
                       x, Wih, Whh, bih, bhh, Wlin, blin, out);
}

// Round 4
// 810.047 us; speedup vs baseline: 1.3362x; 1.3362x over previous
//
#include <hip/hip_runtime.h>

#define TT 2048
#define FF 32
#define CC 32              // chunk length (steps)
#define NCHUNK (TT / CC)   // 64

__device__ __forceinline__ float fast_exp2(float x) {
#if __has_builtin(__builtin_amdgcn_exp2f)
    return __builtin_amdgcn_exp2f(x);
#else
    return exp2f(x);
#endif
}
__device__ __forceinline__ float fast_rcp(float x) {
#if __has_builtin(__builtin_amdgcn_rcpf)
    return __builtin_amdgcn_rcpf(x);
#else
    return 1.0f / x;
#endif
}
__device__ __forceinline__ float fsig(float x) {
    return fast_rcp(1.0f + fast_exp2(-1.442695041f * x));
}
__device__ __forceinline__ float ftanh(float x) {
    return fmaf(2.0f, fast_rcp(1.0f + fast_exp2(-2.885390082f * x)), -1.0f);
}

// lanes<32 receive the value held by lane+32; lanes>=32 receive 0.
// v_permlane32_swap_b32 vdst, vsrc : vdst.hi(lanes 32-63) <-> vsrc.lo(lanes 0-31)
// (VALU op, ~5 cyc — replaces ds_bpermute ~120+ cyc on the recurrence chain)
__device__ __forceinline__ float upper_half(float v) {
    unsigned a = __float_as_uint(v);
    unsigned b = 0u;
    asm volatile("s_nop 1\n\tv_permlane32_swap_b32 %0, %1" : "+v"(a), "+v"(b));
    return __uint_as_float(b);
}

__global__ __launch_bounds__(512, 1)
void lstm_fused(const float* __restrict__ x,
                const float* __restrict__ Wih,
                const float* __restrict__ Whh,
                const float* __restrict__ bih,
                const float* __restrict__ bhh,
                const float* __restrict__ Wlin,
                const float* __restrict__ blin,
                float* __restrict__ out)
{
    // Per-batch LDS rings (2 batches per block). Total = 64+32+16 = 112 KB -> 1 block/CU.
    __shared__ __align__(16) float gbuf[2][2][CC][128]; // gx ring: chunk m -> slot m&1
    __shared__ __align__(16) float xbuf[2][4][CC][32];  // x ring:  chunk m -> slot m&3 (live m-? .. m+)
    __shared__ __align__(16) float hbuf[2][2][CC][32];  // h ring:  chunk m -> slot m&1

    const int tid  = threadIdx.x;
    const int wid  = tid >> 6;
    const int lane = tid & 63;
    const int f    = lane & 31;
    const int p    = lane >> 5;

    // roles: 0=consumer(recurrence) 1=gx 2=out-linear 3=stage
    // Placement balanced for BOTH wid%4 and wid/2 wave->SIMD mappings:
    //   consumers pair with stage (~empty); gx pairs with out.
    int role, my;
    switch (wid) {
        case 0:  role = 0; my = 0; break;
        case 1:  role = 3; my = 1; break;
        case 2:  role = 1; my = 0; break;
        case 3:  role = 2; my = 1; break;
        case 4:  role = 3; my = 0; break;
        case 5:  role = 0; my = 1; break;
        case 6:  role = 2; my = 0; break;
        default: role = 1; my = 1; break;
    }

    const int b = 2 * blockIdx.x + my;
    const float* __restrict__ xb   = x   + (size_t)b * TT * FF;
    float*       __restrict__ outb = out + (size_t)b * TT * FF;

    // ---- per-role weights ----
    float wa[32], wb[32];
    float bias0 = 0.0f, bias1 = 0.0f;
    if (role == 0) {                       // Whh rows lane (i/f) and lane+64 (g/o)
        const float4* A  = (const float4*)(Whh + lane * 32);
        const float4* Bq = (const float4*)(Whh + (lane + 64) * 32);
#pragma unroll
        for (int q = 0; q < 8; q++) {
            float4 a = A[q], c = Bq[q];
            wa[4*q+0]=a.x; wa[4*q+1]=a.y; wa[4*q+2]=a.z; wa[4*q+3]=a.w;
            wb[4*q+0]=c.x; wb[4*q+1]=c.y; wb[4*q+2]=c.z; wb[4*q+3]=c.w;
        }
    } else if (role == 1) {                // Wih rows lane and lane+64, + biases
        const float4* A  = (const float4*)(Wih + lane * 32);
        const float4* Bq = (const float4*)(Wih + (lane + 64) * 32);
#pragma unroll
        for (int q = 0; q < 8; q++) {
            float4 a = A[q], c = Bq[q];
            wa[4*q+0]=a.x; wa[4*q+1]=a.y; wa[4*q+2]=a.z; wa[4*q+3]=a.w;
            wb[4*q+0]=c.x; wb[4*q+1]=c.y; wb[4*q+2]=c.z; wb[4*q+3]=c.w;
        }
        bias0 = bih[lane]      + bhh[lane];
        bias1 = bih[lane + 64] + bhh[lane + 64];
    } else if (role == 2) {                // Wlin: p=0 -> h coeffs (even cols), p=1 -> x coeffs (odd cols)
#pragma unroll
        for (int j = 0; j < 32; j++) wa[j] = Wlin[f * 64 + 2 * j + p];
        bias0 = p ? 0.0f : blin[f];
    }

    // consumer activation constants (lane<32: acc1 row is g -> tanh; lane>=32: o -> sigmoid)
    const float csk = (lane < 32) ? -2.885390082f : -1.442695041f;
    const float cs2 = (lane < 32) ? 2.0f : 1.0f;
    const float cs3 = (lane < 32) ? -1.0f : 0.0f;
    float hv = 0.0f, cv = 0.0f;

    // ---------------- stage (T14 async split: load k+3 to regs, write k+2 to LDS) ----------------
    float4 xr0, xr1, xr2, xr3;
    auto stage_load = [&](int m) {
        const float4* src = (const float4*)(xb + (size_t)m * CC * FF);
        xr0 = src[lane]; xr1 = src[64 + lane]; xr2 = src[128 + lane]; xr3 = src[192 + lane];
    };
    auto stage_write = [&](int m) {
        float4* dst = (float4*)&xbuf[my][m & 3][0][0];
        dst[lane] = xr0; dst[64 + lane] = xr1; dst[128 + lane] = xr2; dst[192 + lane] = xr3;
    };

    // ---------------- gx: one wave does all 128 gate rows (rows lane, lane+64) ----------------
    auto gx_chunk = [&](int m) {
        const float* xs = &xbuf[my][m & 3][0][0];
        float* gb = &gbuf[my][m & 1][0][0];
#pragma unroll 2
        for (int s = 0; s < CC; s++) {
            const float4* x4 = (const float4*)(xs + s * 32);  // uniform addr -> LDS broadcast reads
            float a0 = 0, a1 = 0, a2 = 0, a3 = 0;
#pragma unroll
            for (int q = 0; q < 4; q++) {
                float4 u = x4[2 * q], v = x4[2 * q + 1];
                a0 = fmaf(wa[8*q+0], u.x, a0); a1 = fmaf(wb[8*q+0], u.x, a1);
                a2 = fmaf(wa[8*q+1], u.y, a2); a3 = fmaf(wb[8*q+1], u.y, a3);
                a0 = fmaf(wa[8*q+2], u.z, a0); a1 = fmaf(wb[8*q+2], u.z, a1);
                a2 = fmaf(wa[8*q+3], u.w, a2); a3 = fmaf(wb[8*q+3], u.w, a3);
                a0 = fmaf(wa[8*q+4], v.x, a0); a1 = fmaf(wb[8*q+4], v.x, a1);
                a2 = fmaf(wa[8*q+5], v.y, a2); a3 = fmaf(wb[8*q+5], v.y, a3);
                a0 = fmaf(wa[8*q+6], v.z, a0); a1 = fmaf(wb[8*q+6], v.z, a1);
                a2 = fmaf(wa[8*q+7], v.w, a2); a3 = fmaf(wb[8*q+7], v.w, a3);
            }
            gb[s * 128 + lane]      = (a0 + a2) + bias0;
            gb[s * 128 + 64 + lane] = (a1 + a3) + bias1;
        }
    };

    // ---------------- out-linear: full wave; p=0 half does h-part, p=1 half x-part ----------------
    auto out_chunk = [&](int m) {
        const float* srcb = p ? &xbuf[my][m & 3][0][0] : &hbuf[my][m & 1][0][0];
        float* ob = outb + (size_t)m * CC * FF;
#pragma unroll 2
        for (int s = 0; s < CC; s++) {
            const float4* z4 = (const float4*)(srcb + s * 32); // uniform per half -> broadcast
            float a0 = 0, a1 = 0;
#pragma unroll
            for (int q = 0; q < 4; q++) {
                float4 u = z4[2 * q], v = z4[2 * q + 1];
                a0 = fmaf(wa[8*q+0], u.x, a0); a1 = fmaf(wa[8*q+1], u.y, a1);
                a0 = fmaf(wa[8*q+2], u.z, a0); a1 = fmaf(wa[8*q+3], u.w, a1);
                a0 = fmaf(wa[8*q+4], v.x, a0); a1 = fmaf(wa[8*q+5], v.y, a1);
                a0 = fmaf(wa[8*q+6], v.z, a0); a1 = fmaf(wa[8*q+7], v.w, a1);
            }
            float val   = a0 + a1;
            float other = upper_half(val);          // lanes<32: x-part computed by lane+32
            float y = ftanh(val + other + bias0);
            if (p == 0) ob[s * 32 + f] = y;
        }
    };

    // ---------------- consumer: serial recurrence, no LDS-pipe ops on the chain ----------------
    auto cons_chunk = [&](int k) {
        const float* gb = &gbuf[my][k & 1][0][0];
        float* hb = &hbuf[my][k & 1][0][0];
        float gx0 = gb[lane], gx1 = gb[64 + lane];  // prefetch s=0
#pragma unroll 2
        for (int s = 0; s < CC; s++) {
            float ngx0 = 0.0f, ngx1 = 0.0f;
            if (s + 1 < CC) {                        // prefetch next step's gx (independent of hv)
                ngx0 = gb[(s + 1) * 128 + lane];
                ngx1 = gb[(s + 1) * 128 + 64 + lane];
            }
            unsigned hbits = __float_as_uint(hv);
            float a0 = 0, a1 = 0, a2 = 0, a3 = 0;    // 4 chains: dep depth 16 not 32
#pragma unroll
            for (int j = 0; j < 32; j += 2) {
                float h0 = __uint_as_float(__builtin_amdgcn_readlane(hbits, j));
                float h1 = __uint_as_float(__builtin_amdgcn_readlane(hbits, j + 1));
                a0 = fmaf(wa[j],     h0, a0); a1 = fmaf(wb[j],     h0, a1);
                a2 = fmaf(wa[j + 1], h1, a2); a3 = fmaf(wb[j + 1], h1, a3);
            }
            float g0v = (a0 + a2) + gx0;
            float g1v = (a1 + a3) + gx1;
            float ia = fsig(g0v);                                          // sig(i) lo / sig(f) hi
            float ga = fmaf(cs2, fast_rcp(1.0f + fast_exp2(csk * g1v)), cs3); // tanh(g) lo / sig(o) hi
            float fgv = upper_half(ia);   // lanes<32: sig(f)
            float oov = upper_half(ga);   // lanes<32: sig(o)   (hi lanes get 0 -> hv_hi = 0, benign)
            cv = fmaf(fgv, cv, ia * ga);
            float th = ftanh(cv);
            hv = oov * th;
            if (lane < 32) hb[s * 32 + lane] = hv;
            gx0 = ngx0; gx1 = ngx1;
        }
    };

    // ---- prologue: x0,x1 staged; x2 in regs; gx(0) ready ----
    if (role == 3) { stage_load(0); stage_write(0); stage_load(1); stage_write(1); stage_load(2); }
    __syncthreads();
    if (role == 1) gx_chunk(0);
    __syncthreads();

    // ---- main loop: 65 iterations, one barrier each ----
#pragma unroll 1
    for (int k = 0; k <= NCHUNK; k++) {
        if (role == 0)      { if (k     < NCHUNK) cons_chunk(k); }
        else if (role == 1) { if (k + 1 < NCHUNK) gx_chunk(k + 1); }
        else if (role == 2) { if (k >= 1)         out_chunk(k - 1); }
        else                { if (k + 2 < NCHUNK) stage_write(k + 2);
                              if (k + 3 < NCHUNK) stage_load(k + 3); }
        __syncthreads();
    }
}

extern "C" void kernel_launch(void* const* d_in, const int* in_sizes, int n_in,
                              void* d_out, int out_size, void* d_ws, size_t ws_size,
                              hipStream_t stream) {
    const float* x    = (const float*)d_in[0];
    const float* Wih  = (const float*)d_in[1];
    const float* Whh  = (const float*)d_in[2];
    const float* bih  = (const float*)d_in[3];
    const float* bhh  = (const float*)d_in[4];
    const float* Wlin = (const float*)d_in[5];
    const float* blin = (const float*)d_in[6];
    float* out = (float*)d_out;
    (void)d_ws; (void)ws_size; (void)n_in; (void)out_size;

    const int B = in_sizes[0] / (TT * FF);       // 512
    hipLaunchKernelGGL(lstm_fused, dim3(B / 2), dim3(512), 0, stream,
                       x, Wih, Whh, bih, bhh, Wlin, blin, out);
}